// Round 1
// baseline (1667.702 us; speedup 1.0000x reference)
//
#include <hip/hip_runtime.h>
#include <hip/hip_bf16.h>

#define NSTEPS 40
#define LDS_STRIDE 72  // 64 + 8 bf16 pad: breaks power-of-2 row stride for b64 reads

typedef float  float4v  __attribute__((ext_vector_type(4)));
typedef short  short4v  __attribute__((ext_vector_type(4)));
typedef short  short8v  __attribute__((ext_vector_type(8)));

// tanh(x) = 1 - 2/(exp(2x)+1), via exp2 + rcp (2 transcendentals, 3 VALU)
__device__ __forceinline__ float tanh_fast(float x) {
    float e = __builtin_amdgcn_exp2f(x * 2.8853900817779268f);  // 2*log2(e)
    float r = __builtin_amdgcn_rcpf(e + 1.0f);
    return __builtin_fmaf(-2.0f, r, 1.0f);
}

__device__ __forceinline__ unsigned short f2bf(float x) {
    // compiler emits HW cvt on gfx950; RNE
    __hip_bfloat16 h = __float2bfloat16(x);
    return __builtin_bit_cast(unsigned short, h);
}

__global__ __launch_bounds__(256) void ode_rk4_kernel(
    const float* __restrict__ inp,   // [nrows][64]
    const float* __restrict__ Amat,  // [64][64] row-major
    const float* __restrict__ bvec,  // [64]
    const int* __restrict__ t0p,
    const int* __restrict__ tfp,
    float* __restrict__ out,         // [nrows][64]
    int nrows)
{
    // per-wave private LDS tile: 16 rows x 72 cols bf16
    __shared__ __align__(16) unsigned short lds[4][16][LDS_STRIDE];

    const int tid  = threadIdx.x;
    const int lane = tid & 63;
    const int wave = tid >> 6;
    const int c    = lane & 15;   // col index within 16 (feature sub-col / A-frag row)
    const int g    = lane >> 4;   // lane group 0..3

    const int rowbase = blockIdx.x * 64 + wave * 16;

    const float dt = (float)(tfp[0] - t0p[0]) / (float)NSTEPS;

    // ---- Load entire A^T as MFMA B-fragments (held in registers all kernel).
    // B_op[k][j] = A[j][k]; B-frag lane l elem e: col j = 16t + c,
    // k = kb*32 + g*4 + 16*(e>>2) + (e&3). Same k-permutation used for the
    // A-operand below, so the dot product is layout-permutation invariant.
    short8v bfrag[4][2];
    #pragma unroll
    for (int t = 0; t < 4; ++t) {
        const float* arow = Amat + (16 * t + c) * 64;
        #pragma unroll
        for (int kb = 0; kb < 2; ++kb) {
            short8v f;
            #pragma unroll
            for (int h = 0; h < 2; ++h) {
                float4v v = *reinterpret_cast<const float4v*>(arow + kb * 32 + g * 4 + 16 * h);
                f[4 * h + 0] = (short)f2bf(v[0]);
                f[4 * h + 1] = (short)f2bf(v[1]);
                f[4 * h + 2] = (short)f2bf(v[2]);
                f[4 * h + 3] = (short)f2bf(v[3]);
            }
            bfrag[t][kb] = f;
        }
    }

    // bias for this lane's feature columns j = 16t + c
    float bias[4];
    #pragma unroll
    for (int t = 0; t < 4; ++t) bias[t] = bvec[16 * t + c];

    // ---- Load state y. y[t][r] = Y[m][j], m = 4g + r (batch row), j = 16t + c.
    float4v y[4];
    #pragma unroll
    for (int t = 0; t < 4; ++t) {
        #pragma unroll
        for (int r = 0; r < 4; ++r) {
            int row = rowbase + 4 * g + r;
            if (row >= nrows) row = nrows - 1;  // clamp (harmless duplicate)
            y[t][r] = inp[row * 64 + 16 * t + c];
        }
    }

    float4v kc[4] = {};  // current k_i (zero-init so eval(0) is NaN-free)

    // one f-eval: u = y + coef*kc; kc = tanh(u @ A^T + b)
    auto eval = [&](float coef) {
        // write u (bf16) into this wave's LDS tile, C/D layout -> [m][j]
        #pragma unroll
        for (int t = 0; t < 4; ++t) {
            #pragma unroll
            for (int r = 0; r < 4; ++r) {
                float u = __builtin_fmaf(coef, kc[t][r], y[t][r]);
                lds[wave][4 * g + r][16 * t + c] = f2bf(u);
            }
        }
        asm volatile("" ::: "memory");  // order writes before frag reads (same-wave DS is in-order)
        // read A-operand fragments: lane l: row m' = c, k = kb*32 + g*4 + 16h + {0..3}
        short8v ua[2];
        const unsigned short* myrow = &lds[wave][c][0];
        #pragma unroll
        for (int kb = 0; kb < 2; ++kb) {
            short4v lo = *reinterpret_cast<const short4v*>(myrow + 32 * kb + 4 * g);
            short4v hi = *reinterpret_cast<const short4v*>(myrow + 32 * kb + 4 * g + 16);
            ua[kb] = __builtin_shufflevector(lo, hi, 0, 1, 2, 3, 4, 5, 6, 7);
        }
        asm volatile("" ::: "memory");
        // D[m][j] = sum_k U[m][k] * A[j][k], then tanh(+bias)
        #pragma unroll
        for (int t = 0; t < 4; ++t) {
            float4v d = {0.f, 0.f, 0.f, 0.f};
            d = __builtin_amdgcn_mfma_f32_16x16x32_bf16(ua[0], bfrag[t][0], d, 0, 0, 0);
            d = __builtin_amdgcn_mfma_f32_16x16x32_bf16(ua[1], bfrag[t][1], d, 0, 0, 0);
            #pragma unroll
            for (int r = 0; r < 4; ++r)
                kc[t][r] = tanh_fast(d[r] + bias[t]);
        }
    };

    const float hdt = 0.5f * dt;
    const float dt6 = dt * (1.0f / 6.0f);

    for (int step = 0; step < NSTEPS; ++step) {
        float4v s[4];
        eval(0.0f);           // kc = k1
        #pragma unroll
        for (int t = 0; t < 4; ++t) s[t] = kc[t];
        eval(hdt);            // kc = k2
        #pragma unroll
        for (int t = 0; t < 4; ++t) s[t] += 2.0f * kc[t];
        eval(hdt);            // kc = k3
        #pragma unroll
        for (int t = 0; t < 4; ++t) s[t] += 2.0f * kc[t];
        eval(dt);             // kc = k4
        #pragma unroll
        for (int t = 0; t < 4; ++t) s[t] += kc[t];
        #pragma unroll
        for (int t = 0; t < 4; ++t) y[t] += dt6 * s[t];
    }

    // ---- store
    #pragma unroll
    for (int t = 0; t < 4; ++t) {
        #pragma unroll
        for (int r = 0; r < 4; ++r) {
            int row = rowbase + 4 * g + r;
            if (row < nrows) out[row * 64 + 16 * t + c] = y[t][r];
        }
    }
}

extern "C" void kernel_launch(void* const* d_in, const int* in_sizes, int n_in,
                              void* d_out, int out_size, void* d_ws, size_t ws_size,
                              hipStream_t stream) {
    const float* inp  = (const float*)d_in[0];
    const float* Amat = (const float*)d_in[1];
    const float* bvec = (const float*)d_in[2];
    const int*   t0p  = (const int*)d_in[3];
    const int*   tfp  = (const int*)d_in[4];
    float* out = (float*)d_out;

    const int nrows   = in_sizes[0] / 64;
    const int nblocks = (nrows + 63) / 64;

    ode_rk4_kernel<<<nblocks, 256, 0, stream>>>(inp, Amat, bvec, t0p, tfp, out, nrows);
}

// Round 3
// 1647.113 us; speedup vs baseline: 1.0125x; 1.0125x over previous
//
#include <hip/hip_runtime.h>
#include <hip/hip_bf16.h>

#define NSTEPS 40
#define LSTRIDE 72  // ushorts per LDS row (144 B = 9*16, keeps b128 reads aligned)

typedef float float4v __attribute__((ext_vector_type(4)));
typedef short short8v __attribute__((ext_vector_type(8)));

__device__ __forceinline__ unsigned short f2bf(float x) {
    __hip_bfloat16 h = __float2bfloat16(x);
    unsigned short u;
    __builtin_memcpy(&u, &h, 2);
    return u;
}

__device__ __forceinline__ unsigned int pack2bf(float a, float b) {
    float2 v; v.x = a; v.y = b;
    __hip_bfloat162 p = __float22bfloat162_rn(v);  // v_cvt_pk_bf16_f32
    unsigned int u;
    __builtin_memcpy(&u, &p, 4);
    return u;
}

__global__ __launch_bounds__(256) void ode_rk4_kernel(
    const float* __restrict__ inp,   // [nrows][64]
    const float* __restrict__ Amat,  // [64][64] row-major
    const float* __restrict__ bvec,  // [64]
    const int* __restrict__ t0p,
    const int* __restrict__ tfp,
    float* __restrict__ out,         // [nrows][64]
    int nrows)
{
    // per-wave private tile: U[m][k] stored at ushort position p = 4*(k&15) + (k>>4)
    __shared__ __align__(16) unsigned short lds[4][16][LSTRIDE];

    const int tid  = threadIdx.x;
    const int lane = tid & 63;
    const int wave = tid >> 6;
    const int c    = lane & 15;   // C/D col (feature j sub-col) / A-frag row (batch)
    const int g    = lane >> 4;   // lane group 0..3

    const int rowbase = blockIdx.x * 64 + wave * 16;
    const float dt = (float)(tfp[0] - t0p[0]) / (float)NSTEPS;

    // ---- B fragments of A (held in registers all kernel).
    // Slot (kb,g,e) <-> LDS position p = kb*32 + 8g + e <-> k = 16*(p&3) + (p>>2)
    //   => elem e (e<4):  k = 16e + 8kb + 2g      (pairs contiguous in A row)
    //      elem e+4:      k = 16e + 8kb + 2g + 1
    short8v bfrag[4][2];
    #pragma unroll
    for (int t = 0; t < 4; ++t) {
        const float* arow = Amat + (16 * t + c) * 64;
        #pragma unroll
        for (int kb = 0; kb < 2; ++kb) {
            short8v f;
            #pragma unroll
            for (int h = 0; h < 4; ++h) {
                float lo = arow[16 * h + 8 * kb + 2 * g];
                float hi = arow[16 * h + 8 * kb + 2 * g + 1];
                f[h]     = (short)f2bf(lo);
                f[h + 4] = (short)f2bf(hi);
            }
            bfrag[t][kb] = f;
        }
    }

    // fold bias and 2*log2(e) scale: x = K*d + (K*b)
    const float KK = 2.8853900817779268f;  // 2*log2(e)
    float kb4[4];
    #pragma unroll
    for (int t = 0; t < 4; ++t) kb4[t] = KK * bvec[16 * t + c];

    // ---- state y: y[t][r] = Y[m=4g+r][j=16t+c] (MFMA C/D layout)
    float4v y[4];
    #pragma unroll
    for (int t = 0; t < 4; ++t) {
        #pragma unroll
        for (int r = 0; r < 4; ++r) {
            int row = rowbase + 4 * g + r;
            if (row >= nrows) row = nrows - 1;
            y[t][r] = inp[row * 64 + 16 * t + c];
        }
    }

    float4v kc[4] = {};

    unsigned short* wbase = &lds[wave][4 * g][0];
    const unsigned short* rrow = &lds[wave][c][0];

    // one f-eval: u = y + coef*kc; kc = tanh(u @ A^T + b)
    auto eval = [&](float coef, bool first) {
        #pragma unroll
        for (int r = 0; r < 4; ++r) {
            float u0, u1, u2, u3;
            if (first) {
                u0 = y[0][r]; u1 = y[1][r]; u2 = y[2][r]; u3 = y[3][r];
            } else {
                u0 = __builtin_fmaf(coef, kc[0][r], y[0][r]);
                u1 = __builtin_fmaf(coef, kc[1][r], y[1][r]);
                u2 = __builtin_fmaf(coef, kc[2][r], y[2][r]);
                u3 = __builtin_fmaf(coef, kc[3][r], y[3][r]);
            }
            uint2 w;
            w.x = pack2bf(u0, u1);  // positions 4c, 4c+1  (k=c, 16+c)
            w.y = pack2bf(u2, u3);  // positions 4c+2,4c+3 (k=32+c, 48+c)
            *reinterpret_cast<uint2*>(wbase + r * LSTRIDE + 4 * c) = w;
        }
        asm volatile("" ::: "memory");
        short8v ua0 = *reinterpret_cast<const short8v*>(rrow + 8 * g);
        short8v ua1 = *reinterpret_cast<const short8v*>(rrow + 32 + 8 * g);
        asm volatile("" ::: "memory");
        #pragma unroll
        for (int t = 0; t < 4; ++t) {
            float4v d = {0.f, 0.f, 0.f, 0.f};
            d = __builtin_amdgcn_mfma_f32_16x16x32_bf16(ua0, bfrag[t][0], d, 0, 0, 0);
            d = __builtin_amdgcn_mfma_f32_16x16x32_bf16(ua1, bfrag[t][1], d, 0, 0, 0);
            float4v x = d * KK + kb4[t];          // pk_fma
            float4v e, rr;
            e[0] = __builtin_amdgcn_exp2f(x[0]);
            e[1] = __builtin_amdgcn_exp2f(x[1]);
            e[2] = __builtin_amdgcn_exp2f(x[2]);
            e[3] = __builtin_amdgcn_exp2f(x[3]);
            float4v ep = e + 1.0f;                // pk_add
            rr[0] = __builtin_amdgcn_rcpf(ep[0]);
            rr[1] = __builtin_amdgcn_rcpf(ep[1]);
            rr[2] = __builtin_amdgcn_rcpf(ep[2]);
            rr[3] = __builtin_amdgcn_rcpf(ep[3]);
            kc[t] = rr * -2.0f + 1.0f;            // pk_fma
        }
    };

    const float hdt = 0.5f * dt;
    const float dt6 = dt * (1.0f / 6.0f);

    for (int step = 0; step < NSTEPS; ++step) {
        float4v s[4];
        eval(0.0f, true);     // k1 (u = y, no fma)
        #pragma unroll
        for (int t = 0; t < 4; ++t) s[t] = kc[t];
        eval(hdt, false);     // k2
        #pragma unroll
        for (int t = 0; t < 4; ++t) s[t] += 2.0f * kc[t];
        eval(hdt, false);     // k3
        #pragma unroll
        for (int t = 0; t < 4; ++t) s[t] += 2.0f * kc[t];
        eval(dt, false);      // k4
        #pragma unroll
        for (int t = 0; t < 4; ++t) s[t] += kc[t];
        #pragma unroll
        for (int t = 0; t < 4; ++t) y[t] += dt6 * s[t];
    }

    // ---- store
    #pragma unroll
    for (int t = 0; t < 4; ++t) {
        #pragma unroll
        for (int r = 0; r < 4; ++r) {
            int row = rowbase + 4 * g + r;
            if (row < nrows) out[row * 64 + 16 * t + c] = y[t][r];
        }
    }
}

extern "C" void kernel_launch(void* const* d_in, const int* in_sizes, int n_in,
                              void* d_out, int out_size, void* d_ws, size_t ws_size,
                              hipStream_t stream) {
    const float* inp  = (const float*)d_in[0];
    const float* Amat = (const float*)d_in[1];
    const float* bvec = (const float*)d_in[2];
    const int*   t0p  = (const int*)d_in[3];
    const int*   tfp  = (const int*)d_in[4];
    float* out = (float*)d_out;

    const int nrows   = in_sizes[0] / 64;
    const int nblocks = (nrows + 63) / 64;

    ode_rk4_kernel<<<nblocks, 256, 0, stream>>>(inp, Amat, bvec, t0p, tfp, out, nrows);
}